// Round 2
// baseline (898.129 us; speedup 1.0000x reference)
//
#include <hip/hip_runtime.h>
#include <math.h>

#define PI_F 3.14159265358979323846f

// ---------------------------------------------------------------------------
// N_ORDER=256, PRED_LEN=192, SEQ_LEN=768, ENC_IN=21, B=16, L_s=192<<s, MODES=32
//
// Math (per scale, all linear in x):
//   w_d = A^d B                                   (doubling chain)
//   H_tau[k][i] = sum_{d<=L-1-tau} e^{-2pi i k d/L} w_d[i]
//   A-mat[tau][(ri,k,i)] = { ri=0: c_k(cos(phi)Hr - sin(phi)Hi)
//                            ri=1: -c_k(sin(phi)Hr + cos(phi)Hi) }
//       phi = 2pi k ((191-tau) mod L)/L,  c_0=1/L, c_k=2/L
//   KtilO[tau][o] = A-mat . Wt   (Wt[(ri,k,i)][o] = Wr/Wi[i][o][k]),  K=16384
//   Ktil[tau][p]  = sum_o KtilO[tau][o] E[L-192+p][o]
//   Ktot[taug][p] = sum_s mlp_w[s] Ktil[s][taug-(768-L_s)][p]
//   out[b][p][c]  = sum_taug x[b][taug][c] Ktot[taug][p] + mlp_b
//
// Workspace layout (float offsets):
//   w    [s][d][i]        : 0        len 344064
//   Apow [s][2][65536]    : 344064   len 393216
//   Ktil [s][tau][p]      : 737280   len 258048
//   Ktot [taug][p]        : 995328   len 147456
//   C    [s][tau][o]      : 1142784  len 344064   (KtilO)
//   Wt   [s][ri][k][i][o] : 1486848  len 12582912
//   Amat [tau][16384]     : 14069760 len 12582912 (per-scale reuse, max L=768)
// Total 26,652,672 floats = 106.6 MB (< 108.4 MB proven available)
// ---------------------------------------------------------------------------
#define W_OFF    0
#define AP_OFF   344064
#define KT_OFF   737280
#define KTOT_OFF 995328
#define C_OFF    1142784
#define WT_OFF   1486848
#define A_OFF    14069760
#define WS_FLOATS 26652672

__device__ __forceinline__ int off_w_f(int s)  { return 49152 * ((1 << s) - 1); }
__device__ __forceinline__ int coff_f(int s)   { return 49152 * ((1 << s) - 1); }
__device__ __forceinline__ int ktoff_f(int s)  { return 36864 * ((1 << s) - 1); }

// ---------------------------------------------------------------------------
// Generic 64x64 fp32 GEMM tile, 256 threads, 4x4 microtile.
// BT=true : C += A[M x K] * B[N x K]^T   (both row-major, K fastest)
// BT=false: C += A[M x K] * B[K x N]    (B row-major)
// ATOMIC : accumulate into C with atomicAdd (else overwrite)
// kLen must be a multiple of 16.
// ---------------------------------------------------------------------------
template<bool BT, bool ATOMIC>
__device__ __forceinline__ void gemm_tile(const float* __restrict__ A, int lda,
                                          const float* __restrict__ B, int ldb,
                                          float* __restrict__ C, int ldc,
                                          int M, int N, int m0, int n0, int kLen)
{
    __shared__ float As[16][68];
    __shared__ float Bs[16][68];
    const int tid = threadIdx.x;
    const int tx = tid & 15;
    const int ty = tid >> 4;
    const int r  = tid >> 2;          // 0..63
    const int kq = (tid & 3) << 2;    // 0,4,8,12

    float acc[4][4] = {{0.f,0.f,0.f,0.f},{0.f,0.f,0.f,0.f},
                       {0.f,0.f,0.f,0.f},{0.f,0.f,0.f,0.f}};

    for (int kk = 0; kk < kLen; kk += 16) {
        float4 av = make_float4(0.f, 0.f, 0.f, 0.f);
        if (m0 + r < M)
            av = *(const float4*)(A + (size_t)(m0 + r) * lda + kk + kq);
        As[kq + 0][r] = av.x; As[kq + 1][r] = av.y;
        As[kq + 2][r] = av.z; As[kq + 3][r] = av.w;

        if (BT) {
            float4 bv = make_float4(0.f, 0.f, 0.f, 0.f);
            if (n0 + r < N)
                bv = *(const float4*)(B + (size_t)(n0 + r) * ldb + kk + kq);
            Bs[kq + 0][r] = bv.x; Bs[kq + 1][r] = bv.y;
            Bs[kq + 2][r] = bv.z; Bs[kq + 3][r] = bv.w;
        } else {
            const int kb = tid >> 4;          // 0..15
            const int j4 = (tid & 15) << 2;   // 0..60
            float4 bv = *(const float4*)(B + (size_t)(kk + kb) * ldb + n0 + j4);
            *(float4*)(&Bs[kb][j4]) = bv;
        }
        __syncthreads();

        #pragma unroll
        for (int k = 0; k < 16; ++k) {
            float4 a4 = *(const float4*)(&As[k][ty << 2]);
            float4 b4 = *(const float4*)(&Bs[k][tx << 2]);
            acc[0][0] = fmaf(a4.x, b4.x, acc[0][0]);
            acc[0][1] = fmaf(a4.x, b4.y, acc[0][1]);
            acc[0][2] = fmaf(a4.x, b4.z, acc[0][2]);
            acc[0][3] = fmaf(a4.x, b4.w, acc[0][3]);
            acc[1][0] = fmaf(a4.y, b4.x, acc[1][0]);
            acc[1][1] = fmaf(a4.y, b4.y, acc[1][1]);
            acc[1][2] = fmaf(a4.y, b4.z, acc[1][2]);
            acc[1][3] = fmaf(a4.y, b4.w, acc[1][3]);
            acc[2][0] = fmaf(a4.z, b4.x, acc[2][0]);
            acc[2][1] = fmaf(a4.z, b4.y, acc[2][1]);
            acc[2][2] = fmaf(a4.z, b4.z, acc[2][2]);
            acc[2][3] = fmaf(a4.z, b4.w, acc[2][3]);
            acc[3][0] = fmaf(a4.w, b4.x, acc[3][0]);
            acc[3][1] = fmaf(a4.w, b4.y, acc[3][1]);
            acc[3][2] = fmaf(a4.w, b4.z, acc[3][2]);
            acc[3][3] = fmaf(a4.w, b4.w, acc[3][3]);
        }
        __syncthreads();
    }

    #pragma unroll
    for (int u = 0; u < 4; ++u) {
        int row = m0 + (ty << 2) + u;
        if (row < M) {
            if (ATOMIC) {
                float* cp = C + (size_t)row * ldc + n0 + (tx << 2);
                atomicAdd(cp + 0, acc[u][0]);
                atomicAdd(cp + 1, acc[u][1]);
                atomicAdd(cp + 2, acc[u][2]);
                atomicAdd(cp + 3, acc[u][3]);
            } else {
                float4 cv = make_float4(acc[u][0], acc[u][1], acc[u][2], acc[u][3]);
                *(float4*)(C + (size_t)row * ldc + n0 + (tx << 2)) = cv;
            }
        }
    }
}

// ---------------------------------------------------------------------------
__global__ void k_init(const float* B0, const float* B1, const float* B2, float* ws)
{
    int s = blockIdx.x;
    const float* Bv = (s == 0) ? B0 : (s == 1) ? B1 : B2;
    ws[W_OFF + off_w_f(s) + threadIdx.x] = Bv[threadIdx.x];
}

// ---------------------------------------------------------------------------
// doubling level n:  jump w[2^n + r] = Apow_n @ w[r];  square Apow_{n+1}
// ---------------------------------------------------------------------------
__global__ void k_level(int n, const float* A0, const float* A1, const float* A2,
                        float* ws)
{
    int s = blockIdx.z;
    int L = 192 << s;
    const float* Ain = (s == 0) ? A0 : (s == 1) ? A1 : A2;
    float* wbase = ws + W_OFF + off_w_f(s);
    float* bufA  = ws + AP_OFF + s * 131072;
    float* bufB  = bufA + 65536;
    const float* src = (n == 0) ? Ain : (((n - 1) & 1) ? bufB : bufA);

    int y = blockIdx.y;
    if (y < 4) {
        int p2 = 1 << n;
        if (p2 >= L) return;
        int cnt = min(p2, L - p2);
        int m0 = y * 64;
        if (m0 >= cnt) return;
        gemm_tile<true, false>(wbase, 256, src, 256, wbase + (size_t)p2 * 256, 256,
                               cnt, 256, m0, blockIdx.x * 64, 256);
    } else {
        if ((2 << n) >= L) return;
        float* dst = (n & 1) ? bufB : bufA;
        gemm_tile<false, false>(src, 256, src, 256, dst, 256,
                                256, 256, (y - 4) * 64, blockIdx.x * 64, 256);
    }
}

// ---------------------------------------------------------------------------
// Wt[s][ri][k][i][o] = W[i][o][k]
// ---------------------------------------------------------------------------
__global__ void k_transpose(const float* Wr0, const float* Wi0,
                            const float* Wr1, const float* Wi1,
                            const float* Wr2, const float* Wi2, float* ws)
{
    int bid = blockIdx.x;
    int i  = bid & 255;
    int ri = (bid >> 8) & 1;
    int s  = bid >> 9;
    const float* W;
    if (s == 0)      W = ri ? Wi0 : Wr0;
    else if (s == 1) W = ri ? Wi1 : Wr1;
    else             W = ri ? Wi2 : Wr2;

    int o = threadIdx.x;
    int sri = s * 2 + ri;
    const float* Wrow = W + (size_t)i * 8192 + (size_t)o * 32;
    #pragma unroll
    for (int k = 0; k < 32; ++k) {
        ws[WT_OFF + ((size_t)(sri * 32 + k) * 256 + i) * 256 + o] = Wrow[k];
    }
}

// ---------------------------------------------------------------------------
// zero the C (KtilO) accumulator region: 344064 floats
// ---------------------------------------------------------------------------
__global__ void k_zero(float* ws)
{
    ws[C_OFF + blockIdx.x * 1024 + threadIdx.x * 4 + 0] = 0.f;
    ws[C_OFF + blockIdx.x * 1024 + threadIdx.x * 4 + 1] = 0.f;
    ws[C_OFF + blockIdx.x * 1024 + threadIdx.x * 4 + 2] = 0.f;
    ws[C_OFF + blockIdx.x * 1024 + threadIdx.x * 4 + 3] = 0.f;
}

// ---------------------------------------------------------------------------
// Twiddled suffix scan + phase fold, one scale per launch.
// block = k (32 blocks), 256 threads = i.
//   Hr/Hi accumulate e^{-2pi i k n/L} w_n[i] over n = 0..L-1
//   at n, tau = L-1-n:  write A-mat rows with phase phi = 2pi k((191-tau)%L)/L
// ---------------------------------------------------------------------------
__global__ void k_H(int s, float* __restrict__ ws)
{
    const int k = blockIdx.x;
    const int L = 192 << s;
    const int i = threadIdx.x;

    __shared__ float tc[768];
    __shared__ float tsn[768];
    for (int m = i; m < L; m += 256) {
        float ang = 2.f * PI_F * (float)m / (float)L;
        float ss, cc;
        sincosf(ang, &ss, &cc);
        tc[m] = cc; tsn[m] = ss;
    }
    __syncthreads();

    const float ck = ((k == 0) ? 1.f : 2.f) / (float)L;
    const float* wbase = ws + W_OFF + off_w_f(s);
    float* Ab = ws + A_OFF;

    float Hr = 0.f, Hi = 0.f;
    int mn = 0;                       // (k*n) mod L
    int mphi = (k * (192 % L)) % L;   // k*((191-tau) mod L) mod L at n=0

    for (int n = 0; n < L; ++n) {
        float wv = wbase[(size_t)n * 256 + i];
        float cn = tc[mn], sn = tsn[mn];
        Hr = fmaf(cn, wv, Hr);
        Hi = fmaf(-sn, wv, Hi);

        int tau = L - 1 - n;
        float cp = tc[mphi], sp = tsn[mphi];
        float re = ck * fmaf(cp, Hr, -sp * Hi);
        float im = ck * fmaf(sp, Hr,  cp * Hi);
        Ab[(size_t)tau * 16384 +        k * 256 + i] = re;
        Ab[(size_t)tau * 16384 + 8192 + k * 256 + i] = -im;

        mn += k;   if (mn >= L)   mn -= L;
        mphi += k; if (mphi >= L) mphi -= L;
    }
}

// ---------------------------------------------------------------------------
// KtilO[s][tau][o] += Amat[tau][.] * Wt_s[.][o]   (K = 16384, split-K 16x1024)
// grid (4, L/64, 16)
// ---------------------------------------------------------------------------
__global__ void k_gemmC(int s, float* __restrict__ ws)
{
    const int L = 192 << s;
    const float* Ap = ws + A_OFF + blockIdx.z * 1024;
    const float* Bp = ws + WT_OFF + (size_t)s * 4194304 + (size_t)blockIdx.z * 1024 * 256;
    float* Cp = ws + C_OFF + coff_f(s);
    gemm_tile<false, true>(Ap, 16384, Bp, 256, Cp, 256,
                           L, 256, blockIdx.y * 64, blockIdx.x * 64, 1024);
}

// ---------------------------------------------------------------------------
// Ktil[s][tau][p] = sum_o KtilO[s][tau][o] * E[L-192+p][o]
// grid (3, 21): y -> (s, m-tile)
// ---------------------------------------------------------------------------
__global__ void k_Efold(const float* E0, const float* E1, const float* E2,
                        float* __restrict__ ws)
{
    int y = blockIdx.y;
    int s, mt;
    if (y < 3)      { s = 0; mt = y; }
    else if (y < 9) { s = 1; mt = y - 3; }
    else            { s = 2; mt = y - 9; }
    int L = 192 << s;
    const float* E = (s == 0) ? E0 : (s == 1) ? E1 : E2;
    const float* Ap = ws + C_OFF + coff_f(s);
    const float* Bp = E + (size_t)(L - 192) * 256;
    float* Cp = ws + KT_OFF + ktoff_f(s);
    gemm_tile<true, false>(Ap, 256, Bp, 256, Cp, 192,
                           L, 192, mt * 64, blockIdx.x * 64, 256);
}

// ---------------------------------------------------------------------------
// Ktot[taug][p] = sum_s (taug >= 768-L_s) mlp_w[s] * Ktil[s][taug-(768-L_s)][p]
// ---------------------------------------------------------------------------
__global__ void k_combine(float* ws, const float* mw)
{
    int idx = blockIdx.x * 256 + threadIdx.x;
    if (idx >= 147456) return;
    int tau = idx / 192;
    int p   = idx - tau * 192;
    float sum = 0.f;
    #pragma unroll
    for (int s = 0; s < 3; ++s) {
        int L = 192 << s;
        int off = 768 - L;
        if (tau >= off)
            sum = fmaf(mw[s], ws[KT_OFF + ktoff_f(s) + (size_t)(tau - off) * 192 + p], sum);
    }
    ws[KTOT_OFF + idx] = sum;
}

// ---------------------------------------------------------------------------
// out[b][p][c] = sum_tau x[b][tau][c] * Ktot[tau][p] + mlp_b
// ---------------------------------------------------------------------------
__global__ void k_out(const float* __restrict__ x, const float* __restrict__ ws,
                      const float* __restrict__ mb, float* __restrict__ out)
{
    int bid = blockIdx.x;
    int b = bid / 21;
    int c = bid - b * 21;
    __shared__ float xl[768];
    for (int t = threadIdx.x; t < 768; t += 192)
        xl[t] = x[((size_t)b * 768 + t) * 21 + c];
    __syncthreads();

    int p = threadIdx.x;
    const float* K = ws + KTOT_OFF;
    float acc = 0.f;
    for (int tau = 0; tau < 768; ++tau)
        acc = fmaf(xl[tau], K[(size_t)tau * 192 + p], acc);
    out[((size_t)b * 192 + p) * 21 + c] = acc + mb[0];
}

// ---------------------------------------------------------------------------
extern "C" void kernel_launch(void* const* d_in, const int* in_sizes, int n_in,
                              void* d_out, int out_size, void* d_ws, size_t ws_size,
                              hipStream_t stream)
{
    const float* x   = (const float*)d_in[0];
    const float* A0  = (const float*)d_in[1];
    const float* B0  = (const float*)d_in[2];
    const float* E0  = (const float*)d_in[3];
    const float* Wr0 = (const float*)d_in[4];
    const float* Wi0 = (const float*)d_in[5];
    const float* A1  = (const float*)d_in[6];
    const float* B1  = (const float*)d_in[7];
    const float* E1  = (const float*)d_in[8];
    const float* Wr1 = (const float*)d_in[9];
    const float* Wi1 = (const float*)d_in[10];
    const float* A2  = (const float*)d_in[11];
    const float* B2  = (const float*)d_in[12];
    const float* E2  = (const float*)d_in[13];
    const float* Wr2 = (const float*)d_in[14];
    const float* Wi2 = (const float*)d_in[15];
    const float* mw  = (const float*)d_in[16];
    const float* mb  = (const float*)d_in[17];
    float* ws  = (float*)d_ws;
    float* out = (float*)d_out;

    if (ws_size < (size_t)WS_FLOATS * sizeof(float)) {
        hipMemsetAsync(d_out, 0, (size_t)out_size * sizeof(float), stream);
        return;
    }

    k_init<<<3, 256, 0, stream>>>(B0, B1, B2, ws);
    for (int n = 0; n < 10; ++n)
        k_level<<<dim3(4, 8, 3), 256, 0, stream>>>(n, A0, A1, A2, ws);
    k_transpose<<<1536, 256, 0, stream>>>(Wr0, Wi0, Wr1, Wi1, Wr2, Wi2, ws);
    k_zero<<<336, 256, 0, stream>>>(ws);

    for (int s = 0; s < 3; ++s) {
        k_H<<<32, 256, 0, stream>>>(s, ws);
        k_gemmC<<<dim3(4, (192 << s) / 64, 16), 256, 0, stream>>>(s, ws);
    }

    k_Efold<<<dim3(3, 21), 256, 0, stream>>>(E0, E1, E2, ws);
    k_combine<<<576, 256, 0, stream>>>(ws, mw);
    k_out<<<336, 192, 0, stream>>>(x, ws, mb, out);
}

// Round 3
// 495.914 us; speedup vs baseline: 1.8111x; 1.8111x over previous
//
#include <hip/hip_runtime.h>
#include <math.h>

#define PI_F 3.14159265358979323846f

// ---------------------------------------------------------------------------
// N_ORDER=256, PRED_LEN=192, SEQ_LEN=768, ENC_IN=21, B=16, L_s=192<<s, MODES=32
//
// Pipeline (all linear in x; kernel-matrix construction then one apply):
//   w_d = A^d B                      (doubling chain, 10 levels)
//   Wt[(s,ri,k)][i][o] = W[i][o][k]  (transpose)
//   Y[(s,ri,k)][p][i] = sum_o E[L-192+p][o] Wt[i][o]          (GEMM, 4.8 GF)
//   Qd[(s,ri,k)][d][p] = sum_i w_d[i] Y[p][i]                 (GEMM, 8.5 GF)
//   Z[k][d][p] = sum_{d'<=d} e^{-2pi i k d'/L} Qd[k][d'][p]   (chunked scan)
//   F[s][sidx][k][p] = c_k Re(e^{2pi i k((191-sidx)%L)/L} Z[k][L-1-sidx][p])
//   Ktil[s][sidx][p] = sum_k F
//   Ktot[tau][p] = sum_s mlp_w[s] Ktil[s][tau-(768-L_s)][p]
//   out[b][p][c] = sum_tau x[b][tau][c] Ktot[tau][p] + mlp_b
//
// Workspace layout (float offsets) — identical envelope to the verified r1:
//   w    [s][d][i]        : 0        len 344064
//   Apow [s][2][65536]    : 344064   len 393216
//   Ktil [s][sidx][p]     : 737280   len 258048
//   Ktot [tau][p]         : 995328   len 147456
//   Y    [sri k][p][i]    : 1142784  len 9437184   (dead after k_gemm_Q;
//        S (chunk sums)   : 1142784  len 589824     reused by scan)
//        F (folded)       : 1732608  len 8257536
//   QT region (time-shared):
//     Wt [sri k][i][o]    : 10579968 len 12582912
//     Qd [s][rik][d][p]   : 10579968 len 16515072
// Total 27,095,040 floats (same as round 1, proven to fit)
// ---------------------------------------------------------------------------
#define W_OFF    0
#define AP_OFF   344064
#define KT_OFF   737280
#define KTOT_OFF 995328
#define Y_OFF    1142784
#define S_OFF    1142784
#define F_OFF    1732608
#define QT_OFF   10579968
#define WS_FLOATS 27095040

__device__ __forceinline__ int off_w_f(int s)  { return 49152  * ((1 << s) - 1); }
__device__ __forceinline__ int qoff_f(int s)   { return 2359296 * ((1 << s) - 1); }
__device__ __forceinline__ int ktoff_f(int s)  { return 36864  * ((1 << s) - 1); }
__device__ __forceinline__ int foff_f(int s)   { return 1179648 * ((1 << s) - 1); } // 32*192*L accum

// ---------------------------------------------------------------------------
// 64x64 fp32 GEMM tile, 256 threads, 4x4 microtile, K=256, lda=ldb=256.
// BT=true: C = A @ B^T (both row-major, K fastest). BT=false: C = A @ B.
// ---------------------------------------------------------------------------
template<bool BT>
__device__ __forceinline__ void gemm_tile(const float* __restrict__ A,
                                          const float* __restrict__ B,
                                          float* __restrict__ C,
                                          int M, int N, int ldc, int m0, int n0)
{
    __shared__ float As[16][68];
    __shared__ float Bs[16][68];
    const int tid = threadIdx.x;
    const int tx = tid & 15;
    const int ty = tid >> 4;
    const int r  = tid >> 2;          // 0..63
    const int kq = (tid & 3) << 2;    // 0,4,8,12

    float acc[4][4] = {{0.f,0.f,0.f,0.f},{0.f,0.f,0.f,0.f},
                       {0.f,0.f,0.f,0.f},{0.f,0.f,0.f,0.f}};

    for (int kk = 0; kk < 256; kk += 16) {
        float4 av = make_float4(0.f, 0.f, 0.f, 0.f);
        if (m0 + r < M)
            av = *(const float4*)(A + (size_t)(m0 + r) * 256 + kk + kq);
        As[kq + 0][r] = av.x; As[kq + 1][r] = av.y;
        As[kq + 2][r] = av.z; As[kq + 3][r] = av.w;

        if (BT) {
            float4 bv = make_float4(0.f, 0.f, 0.f, 0.f);
            if (n0 + r < N)
                bv = *(const float4*)(B + (size_t)(n0 + r) * 256 + kk + kq);
            Bs[kq + 0][r] = bv.x; Bs[kq + 1][r] = bv.y;
            Bs[kq + 2][r] = bv.z; Bs[kq + 3][r] = bv.w;
        } else {
            const int kb = tid >> 4;          // 0..15
            const int j4 = (tid & 15) << 2;   // 0..60
            float4 bv = *(const float4*)(B + (size_t)(kk + kb) * 256 + n0 + j4);
            *(float4*)(&Bs[kb][j4]) = bv;
        }
        __syncthreads();

        #pragma unroll
        for (int k = 0; k < 16; ++k) {
            float4 a4 = *(const float4*)(&As[k][ty << 2]);
            float4 b4 = *(const float4*)(&Bs[k][tx << 2]);
            acc[0][0] = fmaf(a4.x, b4.x, acc[0][0]);
            acc[0][1] = fmaf(a4.x, b4.y, acc[0][1]);
            acc[0][2] = fmaf(a4.x, b4.z, acc[0][2]);
            acc[0][3] = fmaf(a4.x, b4.w, acc[0][3]);
            acc[1][0] = fmaf(a4.y, b4.x, acc[1][0]);
            acc[1][1] = fmaf(a4.y, b4.y, acc[1][1]);
            acc[1][2] = fmaf(a4.y, b4.z, acc[1][2]);
            acc[1][3] = fmaf(a4.y, b4.w, acc[1][3]);
            acc[2][0] = fmaf(a4.z, b4.x, acc[2][0]);
            acc[2][1] = fmaf(a4.z, b4.y, acc[2][1]);
            acc[2][2] = fmaf(a4.z, b4.z, acc[2][2]);
            acc[2][3] = fmaf(a4.z, b4.w, acc[2][3]);
            acc[3][0] = fmaf(a4.w, b4.x, acc[3][0]);
            acc[3][1] = fmaf(a4.w, b4.y, acc[3][1]);
            acc[3][2] = fmaf(a4.w, b4.z, acc[3][2]);
            acc[3][3] = fmaf(a4.w, b4.w, acc[3][3]);
        }
        __syncthreads();
    }

    #pragma unroll
    for (int u = 0; u < 4; ++u) {
        int row = m0 + (ty << 2) + u;
        if (row < M) {
            float4 cv = make_float4(acc[u][0], acc[u][1], acc[u][2], acc[u][3]);
            *(float4*)(C + (size_t)row * ldc + n0 + (tx << 2)) = cv;
        }
    }
}

// ---------------------------------------------------------------------------
__global__ void k_init(const float* B0, const float* B1, const float* B2, float* ws)
{
    int s = blockIdx.x;
    const float* Bv = (s == 0) ? B0 : (s == 1) ? B1 : B2;
    ws[W_OFF + off_w_f(s) + threadIdx.x] = Bv[threadIdx.x];
}

// ---------------------------------------------------------------------------
// doubling level n: jump w[2^n + r] = Apow_n @ w[r]; square Apow_{n+1}
// ---------------------------------------------------------------------------
__global__ void k_level(int n, const float* A0, const float* A1, const float* A2,
                        float* ws)
{
    int s = blockIdx.z;
    int L = 192 << s;
    const float* Ain = (s == 0) ? A0 : (s == 1) ? A1 : A2;
    float* wbase = ws + W_OFF + off_w_f(s);
    float* bufA  = ws + AP_OFF + s * 131072;
    float* bufB  = bufA + 65536;
    const float* src = (n == 0) ? Ain : (((n - 1) & 1) ? bufB : bufA);

    int y = blockIdx.y;
    if (y < 4) {
        int p2 = 1 << n;
        if (p2 >= L) return;
        int cnt = min(p2, L - p2);
        int m0 = y * 64;
        if (m0 >= cnt) return;
        gemm_tile<true>(wbase, src, wbase + (size_t)p2 * 256,
                        cnt, 256, 256, m0, blockIdx.x * 64);
    } else {
        if ((2 << n) >= L) return;
        float* dst = (n & 1) ? bufB : bufA;
        gemm_tile<false>(src, src, dst, 256, 256, 256, (y - 4) * 64, blockIdx.x * 64);
    }
}

// ---------------------------------------------------------------------------
// Wt[s][ri][k][i][o] = W[i][o][k]
// ---------------------------------------------------------------------------
__global__ void k_transpose(const float* Wr0, const float* Wi0,
                            const float* Wr1, const float* Wi1,
                            const float* Wr2, const float* Wi2, float* ws)
{
    int bid = blockIdx.x;
    int i  = bid & 255;
    int ri = (bid >> 8) & 1;
    int s  = bid >> 9;
    const float* W;
    if (s == 0)      W = ri ? Wi0 : Wr0;
    else if (s == 1) W = ri ? Wi1 : Wr1;
    else             W = ri ? Wi2 : Wr2;

    int o = threadIdx.x;
    int sri = s * 2 + ri;
    const float* Wrow = W + (size_t)i * 8192 + (size_t)o * 32;
    #pragma unroll
    for (int k = 0; k < 32; ++k) {
        ws[QT_OFF + ((size_t)(sri * 32 + k) * 256 + i) * 256 + o] = Wrow[k];
    }
}

// ---------------------------------------------------------------------------
// Y[s][ri][k][p][i] = sum_o E192[p][o] * Wt[s][ri][k][i][o]
// grid (4, 3, 192): z = (s*2+ri)*32 + k
// ---------------------------------------------------------------------------
__global__ void k_gemm_Y(const float* E0, const float* E1, const float* E2, float* ws)
{
    int z = blockIdx.z;
    int k  = z & 31;
    int ri = (z >> 5) & 1;
    int s  = z >> 6;
    int L = 192 << s;
    const float* E = (s == 0) ? E0 : (s == 1) ? E1 : E2;
    const float* Ap = E + (size_t)(L - 192) * 256;
    const float* Bp = ws + QT_OFF + (size_t)((s * 2 + ri) * 32 + k) * 65536;
    float* Cp = ws + Y_OFF + (size_t)((s * 2 + ri) * 32 + k) * 49152;
    gemm_tile<true>(Ap, Bp, Cp, 192, 256, 256, blockIdx.y * 64, blockIdx.x * 64);
}

// ---------------------------------------------------------------------------
// Qd[s][ri][k][d][p] = sum_i w[s][d][i] * Y[s][ri][k][p][i]
// grid (3, 12, 192)
// ---------------------------------------------------------------------------
__global__ void k_gemm_Q(float* ws)
{
    int z = blockIdx.z;
    int k  = z & 31;
    int ri = (z >> 5) & 1;
    int s  = z >> 6;
    int L = 192 << s;
    int m0 = blockIdx.y * 64;
    if (m0 >= L) return;
    const float* Ap = ws + W_OFF + off_w_f(s);
    const float* Bp = ws + Y_OFF + (size_t)((s * 2 + ri) * 32 + k) * 49152;
    float* Cp = ws + QT_OFF + qoff_f(s) + (size_t)(ri * 32 + k) * L * 192;
    gemm_tile<true>(Ap, Bp, Cp, L, 192, 192, m0, blockIdx.x * 64);
}

// ---------------------------------------------------------------------------
// Pass 1 of chunked twiddled scan: complex chunk sums.
//   S[s][k][c] = sum_{d in chunk c} e^{-2pi i k d/L} Qd[k][d][.]
// grid (16, 32, 3), block 192 (= p)
// ---------------------------------------------------------------------------
__global__ void k_scanA(float* __restrict__ ws)
{
    const int c = blockIdx.x;
    const int k = blockIdx.y;
    const int s = blockIdx.z;
    const int L = 192 << s;
    const int C = L >> 4;           // 12,24,48
    const int p = threadIdx.x;

    __shared__ float twc[768], tws[768];
    for (int m = p; m < L; m += 192) {
        float ang = -2.f * PI_F * (float)m / (float)L;
        float ss, cc; sincosf(ang, &ss, &cc);
        twc[m] = cc; tws[m] = ss;
    }
    __syncthreads();

    const float* Qr = ws + QT_OFF + qoff_f(s) + (size_t)k * L * 192;
    const float* Qi = ws + QT_OFF + qoff_f(s) + (size_t)(32 + k) * L * 192;

    float ar = 0.f, ai = 0.f;
    const int d0 = c * C;
    int ph = (k * d0) % L;
    for (int j = 0; j < C; ++j) {
        int d = d0 + j;
        float qr = Qr[(size_t)d * 192 + p];
        float qi = Qi[(size_t)d * 192 + p];
        float cc = twc[ph], sn = tws[ph];
        ar = fmaf(cc, qr, fmaf(-sn, qi, ar));
        ai = fmaf(cc, qi, fmaf( sn, qr, ai));
        ph += k; if (ph >= L) ph -= L;
    }
    size_t sb = (size_t)((s * 32 + k) * 16 + c) * 384;
    ws[S_OFF + sb + p]       = ar;
    ws[S_OFF + sb + 192 + p] = ai;
}

// ---------------------------------------------------------------------------
// Pass 2: offset = sum of earlier chunk sums; rescan own chunk; fold phase:
//   F[s][sidx][k][p] = c_k * Re( e^{+2pi i k m1/L} * Z_d ), sidx = L-1-d,
//   m1 = (d + 192 - L) mod L
// grid (16, 32, 3), block 192
// ---------------------------------------------------------------------------
__global__ void k_scanB(float* __restrict__ ws)
{
    const int c = blockIdx.x;
    const int k = blockIdx.y;
    const int s = blockIdx.z;
    const int L = 192 << s;
    const int C = L >> 4;
    const int p = threadIdx.x;

    __shared__ float twc[768], tws[768];
    for (int m = p; m < L; m += 192) {
        float ang = -2.f * PI_F * (float)m / (float)L;
        float ss, cc; sincosf(ang, &ss, &cc);
        twc[m] = cc; tws[m] = ss;
    }
    __syncthreads();

    // offset: sum of chunk sums for chunks < c
    float ar = 0.f, ai = 0.f;
    size_t sbase = (size_t)(s * 32 + k) * 16 * 384;
    for (int c2 = 0; c2 < c; ++c2) {
        ar += ws[S_OFF + sbase + (size_t)c2 * 384 + p];
        ai += ws[S_OFF + sbase + (size_t)c2 * 384 + 192 + p];
    }

    const float ck = ((k == 0) ? 1.f : 2.f) / (float)L;
    const float* Qr = ws + QT_OFF + qoff_f(s) + (size_t)k * L * 192;
    const float* Qi = ws + QT_OFF + qoff_f(s) + (size_t)(32 + k) * L * 192;
    float* F = ws + F_OFF + foff_f(s);

    const int d0 = c * C;
    int ph = (k * d0) % L;
    int m1 = d0 + 192 - L; if (m1 < 0) m1 += L;
    int ph2 = (k * m1) % L;
    for (int j = 0; j < C; ++j) {
        int d = d0 + j;
        float qr = Qr[(size_t)d * 192 + p];
        float qi = Qi[(size_t)d * 192 + p];
        float cc = twc[ph], sn = tws[ph];
        ar = fmaf(cc, qr, fmaf(-sn, qi, ar));
        ai = fmaf(cc, qi, fmaf( sn, qr, ai));
        // fold: Re(e^{+i ang2} * (ar + i ai)) with cos=twc[ph2], sin=-tws[ph2]
        float f = ck * fmaf(twc[ph2], ar, tws[ph2] * ai);
        int sidx = L - 1 - d;
        F[((size_t)sidx * 32 + k) * 192 + p] = f;
        ph  += k; if (ph  >= L) ph  -= L;
        ph2 += k; if (ph2 >= L) ph2 -= L;
    }
}

// ---------------------------------------------------------------------------
// Ktil[s][sidx][p] = sum_k F[s][sidx][k][p]
// grid (1344) blocks = (s,sidx), 192 threads
// ---------------------------------------------------------------------------
__global__ void k_kred(float* __restrict__ ws)
{
    int bid = blockIdx.x;
    int s, sidx;
    if (bid < 192)      { s = 0; sidx = bid; }
    else if (bid < 576) { s = 1; sidx = bid - 192; }
    else                { s = 2; sidx = bid - 576; }
    int p = threadIdx.x;
    const float* F = ws + F_OFF + foff_f(s) + (size_t)sidx * 32 * 192;
    float sum = 0.f;
    #pragma unroll
    for (int k = 0; k < 32; ++k)
        sum += F[k * 192 + p];
    ws[KT_OFF + ktoff_f(s) + (size_t)sidx * 192 + p] = sum;
}

// ---------------------------------------------------------------------------
// Ktot[tau][p] = sum_s (tau >= 768-L_s) mlp_w[s] * Ktil[s][tau-(768-L_s)][p]
// ---------------------------------------------------------------------------
__global__ void k_combine(float* ws, const float* mw)
{
    int idx = blockIdx.x * 256 + threadIdx.x;
    if (idx >= 147456) return;
    int tau = idx / 192;
    int p   = idx - tau * 192;
    float sum = 0.f;
    #pragma unroll
    for (int s = 0; s < 3; ++s) {
        int L = 192 << s;
        int off = 768 - L;
        if (tau >= off)
            sum = fmaf(mw[s], ws[KT_OFF + ktoff_f(s) + (size_t)(tau - off) * 192 + p], sum);
    }
    ws[KTOT_OFF + idx] = sum;
}

// ---------------------------------------------------------------------------
// out[b][p][c] = sum_tau x[b][tau][c] * Ktot[tau][p] + mlp_b
// ---------------------------------------------------------------------------
__global__ void k_out(const float* __restrict__ x, const float* __restrict__ ws,
                      const float* __restrict__ mb, float* __restrict__ out)
{
    int bid = blockIdx.x;
    int b = bid / 21;
    int c = bid - b * 21;
    __shared__ float xl[768];
    for (int t = threadIdx.x; t < 768; t += 192)
        xl[t] = x[((size_t)b * 768 + t) * 21 + c];
    __syncthreads();

    int p = threadIdx.x;
    const float* K = ws + KTOT_OFF;
    float acc = 0.f;
    for (int tau = 0; tau < 768; ++tau)
        acc = fmaf(xl[tau], K[(size_t)tau * 192 + p], acc);
    out[((size_t)b * 192 + p) * 21 + c] = acc + mb[0];
}

// ---------------------------------------------------------------------------
extern "C" void kernel_launch(void* const* d_in, const int* in_sizes, int n_in,
                              void* d_out, int out_size, void* d_ws, size_t ws_size,
                              hipStream_t stream)
{
    const float* x   = (const float*)d_in[0];
    const float* A0  = (const float*)d_in[1];
    const float* B0  = (const float*)d_in[2];
    const float* E0  = (const float*)d_in[3];
    const float* Wr0 = (const float*)d_in[4];
    const float* Wi0 = (const float*)d_in[5];
    const float* A1  = (const float*)d_in[6];
    const float* B1  = (const float*)d_in[7];
    const float* E1  = (const float*)d_in[8];
    const float* Wr1 = (const float*)d_in[9];
    const float* Wi1 = (const float*)d_in[10];
    const float* A2  = (const float*)d_in[11];
    const float* B2  = (const float*)d_in[12];
    const float* E2  = (const float*)d_in[13];
    const float* Wr2 = (const float*)d_in[14];
    const float* Wi2 = (const float*)d_in[15];
    const float* mw  = (const float*)d_in[16];
    const float* mb  = (const float*)d_in[17];
    float* ws  = (float*)d_ws;
    float* out = (float*)d_out;

    if (ws_size < (size_t)WS_FLOATS * sizeof(float)) {
        hipMemsetAsync(d_out, 0, (size_t)out_size * sizeof(float), stream);
        return;
    }

    k_init<<<3, 256, 0, stream>>>(B0, B1, B2, ws);
    for (int n = 0; n < 10; ++n)
        k_level<<<dim3(4, 8, 3), 256, 0, stream>>>(n, A0, A1, A2, ws);
    k_transpose<<<1536, 256, 0, stream>>>(Wr0, Wi0, Wr1, Wi1, Wr2, Wi2, ws);
    k_gemm_Y<<<dim3(4, 3, 192), 256, 0, stream>>>(E0, E1, E2, ws);
    k_gemm_Q<<<dim3(3, 12, 192), 256, 0, stream>>>(ws);
    k_scanA<<<dim3(16, 32, 3), 192, 0, stream>>>(ws);
    k_scanB<<<dim3(16, 32, 3), 192, 0, stream>>>(ws);
    k_kred<<<1344, 192, 0, stream>>>(ws);
    k_combine<<<576, 256, 0, stream>>>(ws, mw);
    k_out<<<336, 192, 0, stream>>>(x, ws, mb, out);
}